// Round 10
// baseline (138.403 us; speedup 1.0000x reference)
//
#include <hip/hip_runtime.h>
#include <stdint.h>

typedef unsigned int u32;
typedef unsigned long long u64;

#define MOD_P 2013265921u

// uint2 table offsets (index in uint2 units): (value, shoup) pairs
#define T_A      0        // w^{(i>>7)*(i&127)}        [ka][jc] product table, 16384
#define T_B      16384    // (w^128)^{(i>>7)*(i&127)}  [kb][jc] product table, 16384
#define T_W128P  32768    // (w^128)^i, i<16384
#define T_RP     49152    // (w^16384)^i, i<64  (order-128 stage roots)
#define T_CLP    49216    // c^i, i<16384       (coset low)
#define T_CHP    65600    // c^(16384 i), i<128 (coset high)
#define T_NINV   65728    // (n^-1)

__device__ __forceinline__ u32 mul64mod(u32 a, u32 b){ return (u32)((u64)a * b % MOD_P); }

__device__ u32 powmod(u32 b, u32 e){
  u32 r = 1;
  while (e){ if (e & 1) r = mul64mod(r, b); b = mul64mod(b, b); e >>= 1; }
  return r;
}

__device__ __forceinline__ u32 shoup_of(u32 v){ return (u32)(((u64)v << 32) / MOD_P); }

// reduce a in [0,2P) to [0,P): v_sub + v_min_u32 (unsigned-wrap min trick)
__device__ __forceinline__ u32 redP(u32 a){
  u32 b = a - MOD_P;
  return b < a ? b : a;
}

// Shoup modular multiply; valid for ANY a < 2^32 (w < P): r = a*w mod P in [0,P)
__device__ __forceinline__ u32 mul_shoup(u32 a, uint2 t){
  u32 q = __umulhi(a, t.y);
  u32 r = a * t.x - q * MOD_P;          // exact mod 2^32, true value < 2P
  return redP(r);
}

__device__ __forceinline__ constexpr int rev4(int m){
  return ((m&1)<<3) | ((m&2)<<1) | ((m&4)>>1) | ((m&8)>>3);
}

// DIF butterfly: (x,y) -> (x+y mod P, (x-y)*t mod P); inputs in [0,P)
__device__ __forceinline__ void bf(u32 &x, u32 &y, uint2 t){
  u32 s = redP(x + y);
  u32 d = x - y + MOD_P;                // in (0,2P) — mul_shoup absorbs
  x = s; y = mul_shoup(d, t);
}
// last stage, twiddle=1: y left in [0,2P) (consumer must absorb or redP)
__device__ __forceinline__ void bf0(u32 &x, u32 &y){
  u32 s = redP(x + y);
  u32 d = x - y + MOD_P;
  x = s; y = d;
}

// phase-1: thread rows r = b + 8m (m=0..15), DIF stages h=64,32,16,8
__device__ __forceinline__ void stages_p1(u32 v[16], int b, const uint2* __restrict__ twl){
  #pragma unroll
  for (int m = 0; m < 8; ++m) bf(v[m], v[m+8], twl[b + 8*m]);               // s=6
  #pragma unroll
  for (int g = 0; g < 2; ++g)
    #pragma unroll
    for (int m = 0; m < 4; ++m) bf(v[g*8+m], v[g*8+m+4], twl[(b + 8*m) << 1]); // s=5
  #pragma unroll
  for (int g = 0; g < 4; ++g)
    #pragma unroll
    for (int m = 0; m < 2; ++m) bf(v[g*4+m], v[g*4+m+2], twl[(b + 8*m) << 2]); // s=4
  #pragma unroll
  for (int k = 0; k < 8; ++k) bf(v[2*k], v[2*k+1], twl[b << 3]);            // s=3
}
// phase-2: thread rows r = 16b + m, DIF stages h=4,2,1
__device__ __forceinline__ void stages_p2(u32 v[16], const uint2* __restrict__ twl){
  #pragma unroll
  for (int g = 0; g < 2; ++g)
    #pragma unroll
    for (int m = 0; m < 4; ++m) bf(v[g*8+m], v[g*8+m+4], twl[m << 4]);      // s=2
  #pragma unroll
  for (int g = 0; g < 4; ++g)
    #pragma unroll
    for (int m = 0; m < 2; ++m) bf(v[g*4+m], v[g*4+m+2], twl[m << 5]);      // s=1
  #pragma unroll
  for (int k = 0; k < 8; ++k) bf0(v[2*k], v[2*k+1]);                        // s=0 (e=0)
}

// LDS swizzle for pass C tile [row=jc(128)][col=ka(128)]: 2-way max aliasing
__device__ __forceinline__ int cidx(int row, int a){
  return (row << 7) | (a ^ (row >> 2));
}

// ------------- table generation: ONE powmod per thread, 257 WGs -------------
extern "C" __global__ void k_gen(uint2* __restrict__ tw, const int* __restrict__ f_intt){
  const u32 tid = blockIdx.x * 256 + threadIdx.x;
  const int intt = f_intt[0];
  const u32 MASK = (1u << 21) - 1;
  u32 v; int dst;
  if (tid < 16384){                       // T_A: w^{hi*lo}
    u32 e = (tid >> 7) * (tid & 127);
    if (intt) e = ((1u<<21) - e) & MASK;
    v = powmod(31u, 960u * e); dst = T_A + tid;
  } else if (tid < 32768){                // T_B: w^{128*hi*lo mod 2^21}
    u32 i = tid - 16384;
    u32 e = (((i >> 7) * (i & 127)) << 7) & MASK;
    if (intt) e = ((1u<<21) - e) & MASK;
    v = powmod(31u, 960u * e); dst = T_B + i;
  } else if (tid < 49152){                // T_W128P: w^{128 i mod 2^21}
    u32 i = tid - 32768;
    u32 e = (i << 7) & MASK;
    if (intt) e = ((1u<<21) - e) & MASK;
    v = powmod(31u, 960u * e); dst = T_W128P + i;
  } else if (tid < 65536){                // T_CLP: c^i (c=7 or 7^-1)
    u32 i = tid - 49152;
    v = intt ? powmod(7u, (MOD_P - 1 - i) % (MOD_P - 1)) : powmod(7u, i);
    dst = T_CLP + i;
  } else if (tid < 65664){                // T_CHP: c^{i<<14}
    u32 e = (tid - 65536) << 14;
    v = intt ? powmod(7u, MOD_P - 1 - e) : powmod(7u, e);
    dst = T_CHP + (tid - 65536);
  } else if (tid < 65728){                // T_RP: w^{i<<14}
    u32 e = ((tid - 65664) << 14) & MASK;
    if (intt) e = ((1u<<21) - e) & MASK;
    v = powmod(31u, 960u * e); dst = T_RP + (tid - 65664);
  } else if (tid == 65728){               // NINV
    v = powmod(1u << 21, MOD_P - 2); dst = T_NINV;
  } else return;
  tw[dst] = make_uint2(v, shoup_of(v));
}

// ====== pipelined pass A: WG handles units {g, g+H}; x -> z (contig) ========
extern "C" __global__ void __launch_bounds__(1024, 8) k_passA_p(
    const u32* __restrict__ x, u32* __restrict__ z, const uint2* __restrict__ tw,
    const int* __restrict__ f_intt, const int* __restrict__ f_coset, int H)
{
  __shared__ u32 lds[16384];
  const int t = threadIdx.x;
  const int q = t & 31, rr = t >> 5;
  const int jc = t & 127;
  const int b = __builtin_amdgcn_readfirstlane(t >> 7);
  const int rb = ((b&1)<<2) | (b&2) | ((b&4)>>2);
  const uint2* twl = tw + T_RP;
  const bool pre = (f_intt[0] == 0) && (f_coset[0] != 0);

  int u = blockIdx.x;
  {   // prologue: stage unit u
    const u32* xb = x + ((size_t)(u >> 7) << 21) + ((u & 127) << 7);
    uint4 tmp[4];
    #pragma unroll
    for (int i = 0; i < 4; ++i)
      tmp[i] = *(const uint4*)(xb + ((size_t)(rr + 32*i) << 14) + (q << 2));
    #pragma unroll
    for (int i = 0; i < 4; ++i){
      u32* d = &lds[((rr + 32*i) << 7) | (q << 2)];
      d[0]=redP(tmp[i].x); d[1]=redP(tmp[i].y); d[2]=redP(tmp[i].z); d[3]=redP(tmp[i].w);
    }
  }
  __syncthreads();
  #pragma unroll
  for (int it = 0; it < 2; ++it){
    uint4 tmp[4];
    if (it == 0){                         // issue next unit's loads NOW
      const int un = u + H;
      const u32* xb = x + ((size_t)(un >> 7) << 21) + ((un & 127) << 7);
      #pragma unroll
      for (int i = 0; i < 4; ++i)
        tmp[i] = *(const uint4*)(xb + ((size_t)(rr + 32*i) << 14) + (q << 2));
    }
    const int jb = u & 127;
    u32* zb = z + ((size_t)(u >> 7) << 21) + (jb << 14);
    u32 v[16];
    #pragma unroll
    for (int m = 0; m < 16; ++m) v[m] = lds[((b + 8*m) << 7) | jc];
    if (pre){
      uint2 cl = tw[T_CLP + (jb << 7) + jc];
      #pragma unroll
      for (int m = 0; m < 16; ++m){
        v[m] = mul_shoup(v[m], cl);
        v[m] = mul_shoup(v[m], tw[T_CHP + b + 8*m]);
      }
    }
    stages_p1(v, b, twl);
    #pragma unroll
    for (int m = 0; m < 16; ++m) lds[((b + 8*m) << 7) | jc] = v[m];
    __syncthreads();
    #pragma unroll
    for (int m = 0; m < 16; ++m) v[m] = lds[((16*b + m) << 7) | jc];
    if (it == 0){
      __syncthreads();                    // phase-2 reads done: LDS reusable
      #pragma unroll
      for (int i = 0; i < 4; ++i){        // park staged regs for next unit
        u32* d = &lds[((rr + 32*i) << 7) | (q << 2)];
        d[0]=redP(tmp[i].x); d[1]=redP(tmp[i].y); d[2]=redP(tmp[i].z); d[3]=redP(tmp[i].w);
      }
    }
    stages_p2(v, twl);
    #pragma unroll
    for (int m = 0; m < 16; ++m){
      const int ka = (rev4(m) << 3) | rb;
      u32 vv = mul_shoup(v[m], tw[T_A + (ka << 7) + jc]);
      vv = mul_shoup(vv, tw[T_W128P + ka * jb]);
      zb[(ka << 7) + jc] = vv;
    }
    if (it == 0) __syncthreads();         // staged LDS visible for next iter
    u += H;
  }
}

// ====== pipelined pass B: strided read from z, contiguous write to y ========
extern "C" __global__ void __launch_bounds__(1024, 8) k_passB_p(
    const u32* __restrict__ z, u32* __restrict__ y, const uint2* __restrict__ tw, int H)
{
  __shared__ u32 lds[16384];
  const int t = threadIdx.x;
  const int q = t & 31, rr = t >> 5;
  const int jc = t & 127;
  const int b = __builtin_amdgcn_readfirstlane(t >> 7);
  const int rb = ((b&1)<<2) | (b&2) | ((b&4)>>2);
  const uint2* twl = tw + T_RP;

  int u = blockIdx.x;
  {
    const u32* zb = z + ((size_t)(u >> 7) << 21) + ((u & 127) << 7);
    uint4 tmp[4];
    #pragma unroll
    for (int i = 0; i < 4; ++i)
      tmp[i] = *(const uint4*)(zb + ((size_t)(rr + 32*i) << 14) + (q << 2));
    #pragma unroll
    for (int i = 0; i < 4; ++i){
      u32* d = &lds[((rr + 32*i) << 7) | (q << 2)];
      d[0]=tmp[i].x; d[1]=tmp[i].y; d[2]=tmp[i].z; d[3]=tmp[i].w;
    }
  }
  __syncthreads();
  #pragma unroll
  for (int it = 0; it < 2; ++it){
    uint4 tmp[4];
    if (it == 0){
      const int un = u + H;
      const u32* zb = z + ((size_t)(un >> 7) << 21) + ((un & 127) << 7);
      #pragma unroll
      for (int i = 0; i < 4; ++i)
        tmp[i] = *(const uint4*)(zb + ((size_t)(rr + 32*i) << 14) + (q << 2));
    }
    const int ka = u & 127;
    u32* yb = y + ((size_t)(u >> 7) << 21) + ((size_t)ka << 14);
    u32 v[16];
    #pragma unroll
    for (int m = 0; m < 16; ++m) v[m] = lds[((b + 8*m) << 7) | jc];
    stages_p1(v, b, twl);
    #pragma unroll
    for (int m = 0; m < 16; ++m) lds[((b + 8*m) << 7) | jc] = v[m];
    __syncthreads();
    #pragma unroll
    for (int m = 0; m < 16; ++m) v[m] = lds[((16*b + m) << 7) | jc];
    if (it == 0){
      __syncthreads();
      #pragma unroll
      for (int i = 0; i < 4; ++i){
        u32* d = &lds[((rr + 32*i) << 7) | (q << 2)];
        d[0]=tmp[i].x; d[1]=tmp[i].y; d[2]=tmp[i].z; d[3]=tmp[i].w;
      }
    }
    stages_p2(v, twl);
    #pragma unroll
    for (int m = 0; m < 16; ++m){
      const int kb = (rev4(m) << 3) | rb;
      u32 vv = mul_shoup(v[m], tw[T_B + (kb << 7) + jc]);
      yb[(kb << 7) + jc] = vv;
    }
    if (it == 0) __syncthreads();
    u += H;
  }
}

// ====== pipelined pass C: strided read, NTT over jc, NT strided write =======
extern "C" __global__ void __launch_bounds__(1024, 8) k_passC_p(
    u32* __restrict__ y, const uint2* __restrict__ tw,
    const int* __restrict__ f_intt, const int* __restrict__ f_coset, int H)
{
  __shared__ u32 lds[16384];
  const int t = threadIdx.x;
  const int q = t & 31, rr = t >> 5;
  const int a = t & 127;
  const int b = __builtin_amdgcn_readfirstlane(t >> 7);
  const int rb = ((b&1)<<2) | (b&2) | ((b&4)>>2);
  const uint2* twl = tw + T_RP;
  const int intt = f_intt[0];
  const int coset = f_coset[0];

  int u = blockIdx.x;
  {
    const u32* base = y + ((size_t)(u >> 7) << 21) + ((u & 127) << 7);
    uint4 tmp[4];
    #pragma unroll
    for (int i = 0; i < 4; ++i)
      tmp[i] = *(const uint4*)(base + ((size_t)(rr + 32*i) << 14) + (q << 2));
    #pragma unroll
    for (int i = 0; i < 4; ++i){
      int kaL = rr + 32*i;
      lds[cidx(4*q+0, kaL)] = tmp[i].x;
      lds[cidx(4*q+1, kaL)] = tmp[i].y;
      lds[cidx(4*q+2, kaL)] = tmp[i].z;
      lds[cidx(4*q+3, kaL)] = tmp[i].w;
    }
  }
  __syncthreads();
  #pragma unroll
  for (int it = 0; it < 2; ++it){
    uint4 tmp[4];
    if (it == 0){
      const int un = u + H;
      const u32* base = y + ((size_t)(un >> 7) << 21) + ((un & 127) << 7);
      #pragma unroll
      for (int i = 0; i < 4; ++i)
        tmp[i] = *(const uint4*)(base + ((size_t)(rr + 32*i) << 14) + (q << 2));
    }
    const int kb = u & 127;
    u32* yb = y + ((size_t)(u >> 7) << 21);
    u32 v[16];
    #pragma unroll
    for (int m = 0; m < 16; ++m) v[m] = lds[cidx(b + 8*m, a)];
    stages_p1(v, b, twl);
    #pragma unroll
    for (int m = 0; m < 16; ++m) lds[cidx(b + 8*m, a)] = v[m];
    __syncthreads();
    #pragma unroll
    for (int m = 0; m < 16; ++m) v[m] = lds[cidx(16*b + m, a)];
    if (it == 0){
      __syncthreads();
      #pragma unroll
      for (int i = 0; i < 4; ++i){
        int kaL = rr + 32*i;
        lds[cidx(4*q+0, kaL)] = tmp[i].x;
        lds[cidx(4*q+1, kaL)] = tmp[i].y;
        lds[cidx(4*q+2, kaL)] = tmp[i].z;
        lds[cidx(4*q+3, kaL)] = tmp[i].w;
      }
    }
    stages_p2(v, twl);
    #pragma unroll
    for (int m = 0; m < 16; ++m){
      const int kc = (rev4(m) << 3) | rb;
      u32 vv = v[m];
      if (intt){
        vv = mul_shoup(vv, tw[T_NINV]);
        if (coset){
          vv = mul_shoup(vv, tw[T_CLP + (kb << 7) + a]);
          vv = mul_shoup(vv, tw[T_CHP + kc]);
        }
      } else {
        vv = redP(vv);
      }
      __builtin_nontemporal_store(vv, yb + ((size_t)kc << 14) + (kb << 7) + a);
    }
    if (it == 0) __syncthreads();
    u += H;
  }
}

// =============== fallback kernels (round-9 proven, non-pipelined) ===========
extern "C" __global__ void __launch_bounds__(1024, 8) k_passA(
    const u32* __restrict__ x, u32* __restrict__ y, const uint2* __restrict__ tw,
    const int* __restrict__ f_intt, const int* __restrict__ f_coset)
{
  __shared__ u32 lds[16384];
  const int wg = blockIdx.x;
  const int jb = wg & 127;
  const int batch = wg >> 7;
  const int t = threadIdx.x;
  const u32* xb = x + ((size_t)batch << 21) + (jb << 7);
  u32* yb = y + ((size_t)batch << 21);
  const uint2* twl = tw + T_RP;
  {
    const int q = t & 31, rr = t >> 5;
    uint4 tmp[4];
    #pragma unroll
    for (int i = 0; i < 4; ++i)
      tmp[i] = *(const uint4*)(xb + ((size_t)(rr + 32*i) << 14) + (q << 2));
    #pragma unroll
    for (int i = 0; i < 4; ++i){
      u32* d = &lds[((rr + 32*i) << 7) | (q << 2)];
      d[0] = redP(tmp[i].x); d[1] = redP(tmp[i].y);
      d[2] = redP(tmp[i].z); d[3] = redP(tmp[i].w);
    }
  }
  __syncthreads();
  const int jc = t & 127;
  const int b = __builtin_amdgcn_readfirstlane(t >> 7);
  u32 v[16];
  #pragma unroll
  for (int m = 0; m < 16; ++m) v[m] = lds[((b + 8*m) << 7) | jc];
  if ((f_intt[0] == 0) && (f_coset[0] != 0)){
    uint2 cl = tw[T_CLP + (jb << 7) + jc];
    #pragma unroll
    for (int m = 0; m < 16; ++m){
      v[m] = mul_shoup(v[m], cl);
      v[m] = mul_shoup(v[m], tw[T_CHP + b + 8*m]);
    }
  }
  stages_p1(v, b, twl);
  #pragma unroll
  for (int m = 0; m < 16; ++m) lds[((b + 8*m) << 7) | jc] = v[m];
  __syncthreads();
  #pragma unroll
  for (int m = 0; m < 16; ++m) v[m] = lds[((16*b + m) << 7) | jc];
  stages_p2(v, twl);
  const int rb = ((b&1)<<2) | (b&2) | ((b&4)>>2);
  #pragma unroll
  for (int m = 0; m < 16; ++m){
    const int ka = (rev4(m) << 3) | rb;
    u32 vv = mul_shoup(v[m], tw[T_A + (ka << 7) + jc]);
    vv = mul_shoup(vv, tw[T_W128P + ka * jb]);
    yb[((size_t)ka << 14) + (jb << 7) + jc] = vv;
  }
}

extern "C" __global__ void __launch_bounds__(1024, 8) k_passB(
    u32* __restrict__ y, const uint2* __restrict__ tw)
{
  __shared__ u32 lds[16384];
  const int wg = blockIdx.x;
  const int ka = wg & 127;
  const int batch = wg >> 7;
  const int t = threadIdx.x;
  u32* yb = y + ((size_t)batch << 21) + ((size_t)ka << 14);
  const uint2* twl = tw + T_RP;
  {
    const uint4* s4 = (const uint4*)yb;
    uint4* l4 = (uint4*)lds;
    #pragma unroll
    for (int i = 0; i < 4; ++i) l4[t + 1024*i] = s4[t + 1024*i];
  }
  __syncthreads();
  const int jc = t & 127;
  const int b = __builtin_amdgcn_readfirstlane(t >> 7);
  u32 v[16];
  #pragma unroll
  for (int m = 0; m < 16; ++m) v[m] = lds[((b + 8*m) << 7) | jc];
  stages_p1(v, b, twl);
  #pragma unroll
  for (int m = 0; m < 16; ++m) lds[((b + 8*m) << 7) | jc] = v[m];
  __syncthreads();
  #pragma unroll
  for (int m = 0; m < 16; ++m) v[m] = lds[((16*b + m) << 7) | jc];
  stages_p2(v, twl);
  const int rb = ((b&1)<<2) | (b&2) | ((b&4)>>2);
  #pragma unroll
  for (int m = 0; m < 16; ++m){
    const int kb = (rev4(m) << 3) | rb;
    u32 vv = mul_shoup(v[m], tw[T_B + (kb << 7) + jc]);
    yb[(kb << 7) + jc] = vv;
  }
}

extern "C" __global__ void __launch_bounds__(1024, 8) k_passC(
    u32* __restrict__ y, const uint2* __restrict__ tw,
    const int* __restrict__ f_intt, const int* __restrict__ f_coset)
{
  __shared__ u32 lds[16384];
  const int wg = blockIdx.x;
  const int kb = wg & 127;
  const int batch = wg >> 7;
  u32* yb = y + ((size_t)batch << 21);
  const u32* base = yb + (kb << 7);
  const int t = threadIdx.x;
  {
    const int q = t & 31;
    const int rr = t >> 5;
    uint4 tmp[4];
    #pragma unroll
    for (int i = 0; i < 4; ++i)
      tmp[i] = *(const uint4*)(base + ((size_t)(rr + 32*i) << 14) + (q << 2));
    #pragma unroll
    for (int i = 0; i < 4; ++i){
      int kaL = rr + 32*i;
      lds[cidx(4*q+0, kaL)] = tmp[i].x;
      lds[cidx(4*q+1, kaL)] = tmp[i].y;
      lds[cidx(4*q+2, kaL)] = tmp[i].z;
      lds[cidx(4*q+3, kaL)] = tmp[i].w;
    }
  }
  __syncthreads();
  const int a = t & 127;
  const int b = __builtin_amdgcn_readfirstlane(t >> 7);
  const uint2* twl = tw + T_RP;
  u32 v[16];
  #pragma unroll
  for (int m = 0; m < 16; ++m) v[m] = lds[cidx(b + 8*m, a)];
  stages_p1(v, b, twl);
  #pragma unroll
  for (int m = 0; m < 16; ++m) lds[cidx(b + 8*m, a)] = v[m];
  __syncthreads();
  #pragma unroll
  for (int m = 0; m < 16; ++m) v[m] = lds[cidx(16*b + m, a)];
  stages_p2(v, twl);
  const int rb = ((b&1)<<2) | (b&2) | ((b&4)>>2);
  const int intt = f_intt[0];
  const int coset = f_coset[0];
  #pragma unroll
  for (int m = 0; m < 16; ++m){
    const int kc = (rev4(m) << 3) | rb;
    u32 vv = v[m];
    if (intt){
      vv = mul_shoup(vv, tw[T_NINV]);
      if (coset){
        vv = mul_shoup(vv, tw[T_CLP + (kb << 7) + a]);
        vv = mul_shoup(vv, tw[T_CHP + kc]);
      }
    } else {
      vv = redP(vv);
    }
    __builtin_nontemporal_store(vv, yb + ((size_t)kc << 14) + (kb << 7) + a);
  }
}

extern "C" void kernel_launch(void* const* d_in, const int* in_sizes, int n_in,
                              void* d_out, int out_size, void* d_ws, size_t ws_size,
                              hipStream_t stream)
{
  const u32* x = (const u32*)d_in[0];
  const int* f_intt  = (const int*)d_in[1];
  const int* f_coset = (const int*)d_in[2];
  u32* y   = (u32*)d_out;
  uint2* tw = (uint2*)d_ws;
  const int batch = in_sizes[0] >> 21;     // 8
  const int nunits = batch << 7;           // 1024 tile-units per pass

  k_gen<<<257, 256, 0, stream>>>(tw, f_intt);

  const size_t zoff = (size_t)1 << 20;                 // tables live in [0,1MB)
  const size_t need = zoff + ((size_t)batch << 23);    // + 64MB scratch
  if (ws_size >= need && (nunits & 1) == 0){
    u32* z = (u32*)((char*)d_ws + zoff);
    const int H = nunits >> 1;             // 512 WGs, 2 units each
    k_passA_p<<<H, 1024, 0, stream>>>(x, z, tw, f_intt, f_coset, H);
    k_passB_p<<<H, 1024, 0, stream>>>(z, y, tw, H);
    k_passC_p<<<H, 1024, 0, stream>>>(y, tw, f_intt, f_coset, H);
  } else {
    k_passA<<<nunits, 1024, 0, stream>>>(x, y, tw, f_intt, f_coset);
    k_passB<<<nunits, 1024, 0, stream>>>(y, tw);
    k_passC<<<nunits, 1024, 0, stream>>>(y, tw, f_intt, f_coset);
  }
}

// Round 11
// 130.683 us; speedup vs baseline: 1.0591x; 1.0591x over previous
//
#include <hip/hip_runtime.h>
#include <stdint.h>

typedef unsigned int u32;
typedef unsigned long long u64;

#define MOD_P 2013265921u

// uint2 table offsets (index in uint2 units): (value, shoup) pairs
#define T_A      0        // w^{(i>>7)*(i&127)}        [ka][jc] product table, 16384
#define T_B      16384    // (w^128)^{(i>>7)*(i&127)}  [kb][jc] product table, 16384
#define T_W128P  32768    // (w^128)^i, i<16384
#define T_RP     49152    // (w^16384)^i, i<64  (order-128 stage roots)
#define T_CLP    49216    // c^i, i<16384       (coset low)
#define T_CHP    65600    // c^(16384 i), i<128 (coset high)
#define T_NINV   65728    // (n^-1)

__device__ __forceinline__ u32 mul64mod(u32 a, u32 b){ return (u32)((u64)a * b % MOD_P); }

__device__ u32 powmod(u32 b, u32 e){
  u32 r = 1;
  while (e){ if (e & 1) r = mul64mod(r, b); b = mul64mod(b, b); e >>= 1; }
  return r;
}

__device__ __forceinline__ u32 shoup_of(u32 v){ return (u32)(((u64)v << 32) / MOD_P); }

// reduce a in [0,2P) to [0,P): v_sub + v_min_u32 (unsigned-wrap min trick)
__device__ __forceinline__ u32 redP(u32 a){
  u32 b = a - MOD_P;
  return b < a ? b : a;
}

// Shoup modular multiply; valid for ANY a < 2^32 (w < P): r = a*w mod P in [0,P)
__device__ __forceinline__ u32 mul_shoup(u32 a, uint2 t){
  u32 q = __umulhi(a, t.y);
  u32 r = a * t.x - q * MOD_P;          // exact mod 2^32, true value < 2P
  return redP(r);
}

__device__ __forceinline__ constexpr int rev4(int m){
  return ((m&1)<<3) | ((m&2)<<1) | ((m&4)>>1) | ((m&8)>>3);
}

// DIF butterfly: (x,y) -> (x+y mod P, (x-y)*t mod P); inputs in [0,P)
__device__ __forceinline__ void bf(u32 &x, u32 &y, uint2 t){
  u32 s = redP(x + y);
  u32 d = x - y + MOD_P;                // in (0,2P) — mul_shoup absorbs
  x = s; y = mul_shoup(d, t);
}
// last stage, twiddle=1: y left in [0,2P) (consumer must absorb or redP)
__device__ __forceinline__ void bf0(u32 &x, u32 &y){
  u32 s = redP(x + y);
  u32 d = x - y + MOD_P;
  x = s; y = d;
}

// phase-1: thread rows r = b + 8m (m=0..15), DIF stages h=64,32,16,8
__device__ __forceinline__ void stages_p1(u32 v[16], int b, const uint2* __restrict__ twl){
  #pragma unroll
  for (int m = 0; m < 8; ++m) bf(v[m], v[m+8], twl[b + 8*m]);               // s=6
  #pragma unroll
  for (int g = 0; g < 2; ++g)
    #pragma unroll
    for (int m = 0; m < 4; ++m) bf(v[g*8+m], v[g*8+m+4], twl[(b + 8*m) << 1]); // s=5
  #pragma unroll
  for (int g = 0; g < 4; ++g)
    #pragma unroll
    for (int m = 0; m < 2; ++m) bf(v[g*4+m], v[g*4+m+2], twl[(b + 8*m) << 2]); // s=4
  #pragma unroll
  for (int k = 0; k < 8; ++k) bf(v[2*k], v[2*k+1], twl[b << 3]);            // s=3
}
// phase-2: thread rows r = 16b + m, DIF stages h=4,2,1
__device__ __forceinline__ void stages_p2(u32 v[16], const uint2* __restrict__ twl){
  #pragma unroll
  for (int g = 0; g < 2; ++g)
    #pragma unroll
    for (int m = 0; m < 4; ++m) bf(v[g*8+m], v[g*8+m+4], twl[m << 4]);      // s=2
  #pragma unroll
  for (int g = 0; g < 4; ++g)
    #pragma unroll
    for (int m = 0; m < 2; ++m) bf(v[g*4+m], v[g*4+m+2], twl[m << 5]);      // s=1
  #pragma unroll
  for (int k = 0; k < 8; ++k) bf0(v[2*k], v[2*k+1]);                        // s=0 (e=0)
}

// LDS swizzle for pass C tile [row=jc(128)][col=ka(128)]: 2-way max aliasing
__device__ __forceinline__ int cidx(int row, int a){
  return (row << 7) | (a ^ (row >> 2));
}

// ------------- table generation: ONE powmod per thread, 257 WGs -------------
extern "C" __global__ void k_gen(uint2* __restrict__ tw, const int* __restrict__ f_intt){
  const u32 tid = blockIdx.x * 256 + threadIdx.x;
  const int intt = f_intt[0];
  const u32 MASK = (1u << 21) - 1;
  u32 v; int dst;
  if (tid < 16384){                       // T_A: w^{hi*lo}
    u32 e = (tid >> 7) * (tid & 127);
    if (intt) e = ((1u<<21) - e) & MASK;
    v = powmod(31u, 960u * e); dst = T_A + tid;
  } else if (tid < 32768){                // T_B: w^{128*hi*lo mod 2^21}
    u32 i = tid - 16384;
    u32 e = (((i >> 7) * (i & 127)) << 7) & MASK;
    if (intt) e = ((1u<<21) - e) & MASK;
    v = powmod(31u, 960u * e); dst = T_B + i;
  } else if (tid < 49152){                // T_W128P: w^{128 i mod 2^21}
    u32 i = tid - 32768;
    u32 e = (i << 7) & MASK;
    if (intt) e = ((1u<<21) - e) & MASK;
    v = powmod(31u, 960u * e); dst = T_W128P + i;
  } else if (tid < 65536){                // T_CLP: c^i (c=7 or 7^-1)
    u32 i = tid - 49152;
    v = intt ? powmod(7u, (MOD_P - 1 - i) % (MOD_P - 1)) : powmod(7u, i);
    dst = T_CLP + i;
  } else if (tid < 65664){                // T_CHP: c^{i<<14}
    u32 e = (tid - 65536) << 14;
    v = intt ? powmod(7u, MOD_P - 1 - e) : powmod(7u, e);
    dst = T_CHP + (tid - 65536);
  } else if (tid < 65728){                // T_RP: w^{i<<14}
    u32 e = ((tid - 65664) << 14) & MASK;
    if (intt) e = ((1u<<21) - e) & MASK;
    v = powmod(31u, 960u * e); dst = T_RP + (tid - 65664);
  } else if (tid == 65728){               // NINV
    v = powmod(1u << 21, MOD_P - 2); dst = T_NINV;
  } else return;
  tw[dst] = make_uint2(v, shoup_of(v));
}

// ====== pipelined pass A: WG handles units {g, g+H}; x -> y (in-place-free) =
// prefetch of unit g+H overlaps unit g's compute; unit g+H is owned by this
// WG only, so the prefetch is race-free.
extern "C" __global__ void __launch_bounds__(1024, 8) k_passA_p(
    const u32* __restrict__ x, u32* __restrict__ y, const uint2* __restrict__ tw,
    const int* __restrict__ f_intt, const int* __restrict__ f_coset, int H)
{
  __shared__ u32 lds[16384];
  const int t = threadIdx.x;
  const int q = t & 31, rr = t >> 5;
  const int jc = t & 127;
  const int b = __builtin_amdgcn_readfirstlane(t >> 7);
  const int rb = ((b&1)<<2) | (b&2) | ((b&4)>>2);
  const uint2* twl = tw + T_RP;
  const bool pre = (f_intt[0] == 0) && (f_coset[0] != 0);

  int u = blockIdx.x;
  {   // prologue: stage unit u
    const u32* xb = x + ((size_t)(u >> 7) << 21) + ((u & 127) << 7);
    uint4 tmp[4];
    #pragma unroll
    for (int i = 0; i < 4; ++i)
      tmp[i] = *(const uint4*)(xb + ((size_t)(rr + 32*i) << 14) + (q << 2));
    #pragma unroll
    for (int i = 0; i < 4; ++i){
      u32* d = &lds[((rr + 32*i) << 7) | (q << 2)];
      d[0]=redP(tmp[i].x); d[1]=redP(tmp[i].y); d[2]=redP(tmp[i].z); d[3]=redP(tmp[i].w);
    }
  }
  __syncthreads();
  #pragma unroll
  for (int it = 0; it < 2; ++it){
    uint4 tmp[4];
    if (it == 0){                         // issue next unit's loads NOW
      const int un = u + H;
      const u32* xb = x + ((size_t)(un >> 7) << 21) + ((un & 127) << 7);
      #pragma unroll
      for (int i = 0; i < 4; ++i)
        tmp[i] = *(const uint4*)(xb + ((size_t)(rr + 32*i) << 14) + (q << 2));
    }
    const int jb = u & 127;
    u32* yb = y + ((size_t)(u >> 7) << 21);
    u32 v[16];
    #pragma unroll
    for (int m = 0; m < 16; ++m) v[m] = lds[((b + 8*m) << 7) | jc];
    if (pre){
      uint2 cl = tw[T_CLP + (jb << 7) + jc];
      #pragma unroll
      for (int m = 0; m < 16; ++m){
        v[m] = mul_shoup(v[m], cl);
        v[m] = mul_shoup(v[m], tw[T_CHP + b + 8*m]);
      }
    }
    stages_p1(v, b, twl);
    #pragma unroll
    for (int m = 0; m < 16; ++m) lds[((b + 8*m) << 7) | jc] = v[m];
    __syncthreads();
    #pragma unroll
    for (int m = 0; m < 16; ++m) v[m] = lds[((16*b + m) << 7) | jc];
    if (it == 0){
      __syncthreads();                    // phase-2 reads done: LDS reusable
      #pragma unroll
      for (int i = 0; i < 4; ++i){        // park staged regs for next unit
        u32* d = &lds[((rr + 32*i) << 7) | (q << 2)];
        d[0]=redP(tmp[i].x); d[1]=redP(tmp[i].y); d[2]=redP(tmp[i].z); d[3]=redP(tmp[i].w);
      }
    }
    stages_p2(v, twl);
    #pragma unroll
    for (int m = 0; m < 16; ++m){
      const int ka = (rev4(m) << 3) | rb;
      u32 vv = mul_shoup(v[m], tw[T_A + (ka << 7) + jc]);
      vv = mul_shoup(vv, tw[T_W128P + ka * jb]);
      yb[((size_t)ka << 14) + (jb << 7) + jc] = vv;
    }
    if (it == 0) __syncthreads();         // staged LDS visible for next iter
    u += H;
  }
}

// ====== pipelined pass B: y slabs in-place (contiguous read & write) ========
extern "C" __global__ void __launch_bounds__(1024, 8) k_passB_p(
    u32* __restrict__ y, const uint2* __restrict__ tw, int H)
{
  __shared__ u32 lds[16384];
  const int t = threadIdx.x;
  const int jc = t & 127;
  const int b = __builtin_amdgcn_readfirstlane(t >> 7);
  const int rb = ((b&1)<<2) | (b&2) | ((b&4)>>2);
  const uint2* twl = tw + T_RP;

  int u = blockIdx.x;
  {   // prologue: stage own slab, fully contiguous
    const uint4* s4 = (const uint4*)(y + ((size_t)(u >> 7) << 21) + ((size_t)(u & 127) << 14));
    uint4* l4 = (uint4*)lds;
    #pragma unroll
    for (int i = 0; i < 4; ++i) l4[t + 1024*i] = s4[t + 1024*i];
  }
  __syncthreads();
  #pragma unroll
  for (int it = 0; it < 2; ++it){
    uint4 tmp[4];
    if (it == 0){                         // prefetch own second slab
      const int un = u + H;
      const uint4* s4 = (const uint4*)(y + ((size_t)(un >> 7) << 21) + ((size_t)(un & 127) << 14));
      #pragma unroll
      for (int i = 0; i < 4; ++i) tmp[i] = s4[t + 1024*i];
    }
    u32* yb = y + ((size_t)(u >> 7) << 21) + ((size_t)(u & 127) << 14);
    u32 v[16];
    #pragma unroll
    for (int m = 0; m < 16; ++m) v[m] = lds[((b + 8*m) << 7) | jc];
    stages_p1(v, b, twl);
    #pragma unroll
    for (int m = 0; m < 16; ++m) lds[((b + 8*m) << 7) | jc] = v[m];
    __syncthreads();
    #pragma unroll
    for (int m = 0; m < 16; ++m) v[m] = lds[((16*b + m) << 7) | jc];
    if (it == 0){
      __syncthreads();
      uint4* l4 = (uint4*)lds;
      #pragma unroll
      for (int i = 0; i < 4; ++i) l4[t + 1024*i] = tmp[i];
    }
    stages_p2(v, twl);
    #pragma unroll
    for (int m = 0; m < 16; ++m){
      const int kb = (rev4(m) << 3) | rb;
      u32 vv = mul_shoup(v[m], tw[T_B + (kb << 7) + jc]);
      yb[(kb << 7) + jc] = vv;
    }
    if (it == 0) __syncthreads();
    u += H;
  }
}

// ====== pipelined pass C: strided read, NTT over jc, NT strided write =======
extern "C" __global__ void __launch_bounds__(1024, 8) k_passC_p(
    u32* __restrict__ y, const uint2* __restrict__ tw,
    const int* __restrict__ f_intt, const int* __restrict__ f_coset, int H)
{
  __shared__ u32 lds[16384];
  const int t = threadIdx.x;
  const int q = t & 31, rr = t >> 5;
  const int a = t & 127;
  const int b = __builtin_amdgcn_readfirstlane(t >> 7);
  const int rb = ((b&1)<<2) | (b&2) | ((b&4)>>2);
  const uint2* twl = tw + T_RP;
  const int intt = f_intt[0];
  const int coset = f_coset[0];

  int u = blockIdx.x;
  {
    const u32* base = y + ((size_t)(u >> 7) << 21) + ((u & 127) << 7);
    uint4 tmp[4];
    #pragma unroll
    for (int i = 0; i < 4; ++i)
      tmp[i] = *(const uint4*)(base + ((size_t)(rr + 32*i) << 14) + (q << 2));
    #pragma unroll
    for (int i = 0; i < 4; ++i){
      int kaL = rr + 32*i;
      lds[cidx(4*q+0, kaL)] = tmp[i].x;
      lds[cidx(4*q+1, kaL)] = tmp[i].y;
      lds[cidx(4*q+2, kaL)] = tmp[i].z;
      lds[cidx(4*q+3, kaL)] = tmp[i].w;
    }
  }
  __syncthreads();
  #pragma unroll
  for (int it = 0; it < 2; ++it){
    uint4 tmp[4];
    if (it == 0){                         // prefetch own second unit (race-free)
      const int un = u + H;
      const u32* base = y + ((size_t)(un >> 7) << 21) + ((un & 127) << 7);
      #pragma unroll
      for (int i = 0; i < 4; ++i)
        tmp[i] = *(const uint4*)(base + ((size_t)(rr + 32*i) << 14) + (q << 2));
    }
    const int kb = u & 127;
    u32* yb = y + ((size_t)(u >> 7) << 21);
    u32 v[16];
    #pragma unroll
    for (int m = 0; m < 16; ++m) v[m] = lds[cidx(b + 8*m, a)];
    stages_p1(v, b, twl);
    #pragma unroll
    for (int m = 0; m < 16; ++m) lds[cidx(b + 8*m, a)] = v[m];
    __syncthreads();
    #pragma unroll
    for (int m = 0; m < 16; ++m) v[m] = lds[cidx(16*b + m, a)];
    if (it == 0){
      __syncthreads();
      #pragma unroll
      for (int i = 0; i < 4; ++i){
        int kaL = rr + 32*i;
        lds[cidx(4*q+0, kaL)] = tmp[i].x;
        lds[cidx(4*q+1, kaL)] = tmp[i].y;
        lds[cidx(4*q+2, kaL)] = tmp[i].z;
        lds[cidx(4*q+3, kaL)] = tmp[i].w;
      }
    }
    stages_p2(v, twl);
    #pragma unroll
    for (int m = 0; m < 16; ++m){
      const int kc = (rev4(m) << 3) | rb;
      u32 vv = v[m];
      if (intt){
        vv = mul_shoup(vv, tw[T_NINV]);
        if (coset){
          vv = mul_shoup(vv, tw[T_CLP + (kb << 7) + a]);
          vv = mul_shoup(vv, tw[T_CHP + kc]);
        }
      } else {
        vv = redP(vv);
      }
      __builtin_nontemporal_store(vv, yb + ((size_t)kc << 14) + (kb << 7) + a);
    }
    if (it == 0) __syncthreads();
    u += H;
  }
}

// =============== fallback kernels (round-8 proven, non-pipelined) ===========
extern "C" __global__ void __launch_bounds__(1024, 8) k_passA(
    const u32* __restrict__ x, u32* __restrict__ y, const uint2* __restrict__ tw,
    const int* __restrict__ f_intt, const int* __restrict__ f_coset)
{
  __shared__ u32 lds[16384];
  const int wg = blockIdx.x;
  const int jb = wg & 127;
  const int batch = wg >> 7;
  const int t = threadIdx.x;
  const u32* xb = x + ((size_t)batch << 21) + (jb << 7);
  u32* yb = y + ((size_t)batch << 21);
  const uint2* twl = tw + T_RP;
  {
    const int q = t & 31, rr = t >> 5;
    uint4 tmp[4];
    #pragma unroll
    for (int i = 0; i < 4; ++i)
      tmp[i] = *(const uint4*)(xb + ((size_t)(rr + 32*i) << 14) + (q << 2));
    #pragma unroll
    for (int i = 0; i < 4; ++i){
      u32* d = &lds[((rr + 32*i) << 7) | (q << 2)];
      d[0] = redP(tmp[i].x); d[1] = redP(tmp[i].y);
      d[2] = redP(tmp[i].z); d[3] = redP(tmp[i].w);
    }
  }
  __syncthreads();
  const int jc = t & 127;
  const int b = __builtin_amdgcn_readfirstlane(t >> 7);
  u32 v[16];
  #pragma unroll
  for (int m = 0; m < 16; ++m) v[m] = lds[((b + 8*m) << 7) | jc];
  if ((f_intt[0] == 0) && (f_coset[0] != 0)){
    uint2 cl = tw[T_CLP + (jb << 7) + jc];
    #pragma unroll
    for (int m = 0; m < 16; ++m){
      v[m] = mul_shoup(v[m], cl);
      v[m] = mul_shoup(v[m], tw[T_CHP + b + 8*m]);
    }
  }
  stages_p1(v, b, twl);
  #pragma unroll
  for (int m = 0; m < 16; ++m) lds[((b + 8*m) << 7) | jc] = v[m];
  __syncthreads();
  #pragma unroll
  for (int m = 0; m < 16; ++m) v[m] = lds[((16*b + m) << 7) | jc];
  stages_p2(v, twl);
  const int rb = ((b&1)<<2) | (b&2) | ((b&4)>>2);
  #pragma unroll
  for (int m = 0; m < 16; ++m){
    const int ka = (rev4(m) << 3) | rb;
    u32 vv = mul_shoup(v[m], tw[T_A + (ka << 7) + jc]);
    vv = mul_shoup(vv, tw[T_W128P + ka * jb]);
    yb[((size_t)ka << 14) + (jb << 7) + jc] = vv;
  }
}

extern "C" __global__ void __launch_bounds__(1024, 8) k_passB(
    u32* __restrict__ y, const uint2* __restrict__ tw)
{
  __shared__ u32 lds[16384];
  const int wg = blockIdx.x;
  const int ka = wg & 127;
  const int batch = wg >> 7;
  const int t = threadIdx.x;
  u32* yb = y + ((size_t)batch << 21) + ((size_t)ka << 14);
  const uint2* twl = tw + T_RP;
  {
    const uint4* s4 = (const uint4*)yb;
    uint4* l4 = (uint4*)lds;
    #pragma unroll
    for (int i = 0; i < 4; ++i) l4[t + 1024*i] = s4[t + 1024*i];
  }
  __syncthreads();
  const int jc = t & 127;
  const int b = __builtin_amdgcn_readfirstlane(t >> 7);
  u32 v[16];
  #pragma unroll
  for (int m = 0; m < 16; ++m) v[m] = lds[((b + 8*m) << 7) | jc];
  stages_p1(v, b, twl);
  #pragma unroll
  for (int m = 0; m < 16; ++m) lds[((b + 8*m) << 7) | jc] = v[m];
  __syncthreads();
  #pragma unroll
  for (int m = 0; m < 16; ++m) v[m] = lds[((16*b + m) << 7) | jc];
  stages_p2(v, twl);
  const int rb = ((b&1)<<2) | (b&2) | ((b&4)>>2);
  #pragma unroll
  for (int m = 0; m < 16; ++m){
    const int kb = (rev4(m) << 3) | rb;
    u32 vv = mul_shoup(v[m], tw[T_B + (kb << 7) + jc]);
    yb[(kb << 7) + jc] = vv;
  }
}

extern "C" __global__ void __launch_bounds__(1024, 8) k_passC(
    u32* __restrict__ y, const uint2* __restrict__ tw,
    const int* __restrict__ f_intt, const int* __restrict__ f_coset)
{
  __shared__ u32 lds[16384];
  const int wg = blockIdx.x;
  const int kb = wg & 127;
  const int batch = wg >> 7;
  u32* yb = y + ((size_t)batch << 21);
  const u32* base = yb + (kb << 7);
  const int t = threadIdx.x;
  {
    const int q = t & 31;
    const int rr = t >> 5;
    uint4 tmp[4];
    #pragma unroll
    for (int i = 0; i < 4; ++i)
      tmp[i] = *(const uint4*)(base + ((size_t)(rr + 32*i) << 14) + (q << 2));
    #pragma unroll
    for (int i = 0; i < 4; ++i){
      int kaL = rr + 32*i;
      lds[cidx(4*q+0, kaL)] = tmp[i].x;
      lds[cidx(4*q+1, kaL)] = tmp[i].y;
      lds[cidx(4*q+2, kaL)] = tmp[i].z;
      lds[cidx(4*q+3, kaL)] = tmp[i].w;
    }
  }
  __syncthreads();
  const int a = t & 127;
  const int b = __builtin_amdgcn_readfirstlane(t >> 7);
  const uint2* twl = tw + T_RP;
  u32 v[16];
  #pragma unroll
  for (int m = 0; m < 16; ++m) v[m] = lds[cidx(b + 8*m, a)];
  stages_p1(v, b, twl);
  #pragma unroll
  for (int m = 0; m < 16; ++m) lds[cidx(b + 8*m, a)] = v[m];
  __syncthreads();
  #pragma unroll
  for (int m = 0; m < 16; ++m) v[m] = lds[cidx(16*b + m, a)];
  stages_p2(v, twl);
  const int rb = ((b&1)<<2) | (b&2) | ((b&4)>>2);
  const int intt = f_intt[0];
  const int coset = f_coset[0];
  #pragma unroll
  for (int m = 0; m < 16; ++m){
    const int kc = (rev4(m) << 3) | rb;
    u32 vv = v[m];
    if (intt){
      vv = mul_shoup(vv, tw[T_NINV]);
      if (coset){
        vv = mul_shoup(vv, tw[T_CLP + (kb << 7) + a]);
        vv = mul_shoup(vv, tw[T_CHP + kc]);
      }
    } else {
      vv = redP(vv);
    }
    __builtin_nontemporal_store(vv, yb + ((size_t)kc << 14) + (kb << 7) + a);
  }
}

extern "C" void kernel_launch(void* const* d_in, const int* in_sizes, int n_in,
                              void* d_out, int out_size, void* d_ws, size_t ws_size,
                              hipStream_t stream)
{
  const u32* x = (const u32*)d_in[0];
  const int* f_intt  = (const int*)d_in[1];
  const int* f_coset = (const int*)d_in[2];
  u32* y   = (u32*)d_out;
  uint2* tw = (uint2*)d_ws;
  const int batch = in_sizes[0] >> 21;     // 8
  const int nunits = batch << 7;           // 1024 tile-units per pass

  k_gen<<<257, 256, 0, stream>>>(tw, f_intt);

  if ((nunits & 1) == 0){
    const int H = nunits >> 1;             // 512 WGs, 2 units each, in-place
    k_passA_p<<<H, 1024, 0, stream>>>(x, y, tw, f_intt, f_coset, H);
    k_passB_p<<<H, 1024, 0, stream>>>(y, tw, H);
    k_passC_p<<<H, 1024, 0, stream>>>(y, tw, f_intt, f_coset, H);
  } else {
    k_passA<<<nunits, 1024, 0, stream>>>(x, y, tw, f_intt, f_coset);
    k_passB<<<nunits, 1024, 0, stream>>>(y, tw);
    k_passC<<<nunits, 1024, 0, stream>>>(y, tw, f_intt, f_coset);
  }
}

// Round 12
// 103.142 us; speedup vs baseline: 1.3419x; 1.2670x over previous
//
#include <hip/hip_runtime.h>
#include <stdint.h>

typedef unsigned int u32;
typedef unsigned long long u64;

#define MOD_P 2013265921u

// uint2 table offsets (index in uint2 units): (value, shoup) pairs
#define T_A      0        // w^{(i>>7)*(i&127)}        [ka][jc] product table, 16384
#define T_B      16384    // (w^128)^{(i>>7)*(i&127)}  [kb][jc] product table, 16384
#define T_W128P  32768    // (w^128)^i, i<16384
#define T_RP     49152    // (w^16384)^i, i<64  (order-128 stage roots)
#define T_CLP    49216    // c^i, i<16384       (coset low)
#define T_CHP    65600    // c^(16384 i), i<128 (coset high)
#define T_NINV   65728    // (n^-1)

__device__ __forceinline__ u32 mul64mod(u32 a, u32 b){ return (u32)((u64)a * b % MOD_P); }

__device__ u32 powmod(u32 b, u32 e){
  u32 r = 1;
  while (e){ if (e & 1) r = mul64mod(r, b); b = mul64mod(b, b); e >>= 1; }
  return r;
}

__device__ __forceinline__ u32 shoup_of(u32 v){ return (u32)(((u64)v << 32) / MOD_P); }

// reduce a in [0,2P) to [0,P): v_sub + v_min_u32 (unsigned-wrap min trick)
__device__ __forceinline__ u32 redP(u32 a){
  u32 b = a - MOD_P;
  return b < a ? b : a;
}

// Shoup modular multiply; valid for ANY a < 2^32 (w < P): r = a*w mod P in [0,P)
__device__ __forceinline__ u32 mul_shoup(u32 a, uint2 t){
  u32 q = __umulhi(a, t.y);
  u32 r = a * t.x - q * MOD_P;          // exact mod 2^32, true value < 2P
  return redP(r);
}

__device__ __forceinline__ constexpr int rev4(int m){
  return ((m&1)<<3) | ((m&2)<<1) | ((m&4)>>1) | ((m&8)>>3);
}

// DIF butterfly: (x,y) -> (x+y mod P, (x-y)*t mod P); inputs in [0,P)
__device__ __forceinline__ void bf(u32 &x, u32 &y, uint2 t){
  u32 s = redP(x + y);
  u32 d = x - y + MOD_P;                // in (0,2P) — mul_shoup absorbs
  x = s; y = mul_shoup(d, t);
}
// last stage, twiddle=1: y left in [0,2P) (consumer must absorb or redP)
__device__ __forceinline__ void bf0(u32 &x, u32 &y){
  u32 s = redP(x + y);
  u32 d = x - y + MOD_P;
  x = s; y = d;
}

// phase-1: thread rows r = b + 8m (m=0..15), DIF stages h=64,32,16,8
__device__ __forceinline__ void stages_p1(u32 v[16], int b, const uint2* __restrict__ twl){
  #pragma unroll
  for (int m = 0; m < 8; ++m) bf(v[m], v[m+8], twl[b + 8*m]);               // s=6
  #pragma unroll
  for (int g = 0; g < 2; ++g)
    #pragma unroll
    for (int m = 0; m < 4; ++m) bf(v[g*8+m], v[g*8+m+4], twl[(b + 8*m) << 1]); // s=5
  #pragma unroll
  for (int g = 0; g < 4; ++g)
    #pragma unroll
    for (int m = 0; m < 2; ++m) bf(v[g*4+m], v[g*4+m+2], twl[(b + 8*m) << 2]); // s=4
  #pragma unroll
  for (int k = 0; k < 8; ++k) bf(v[2*k], v[2*k+1], twl[b << 3]);            // s=3
}
// phase-2: thread rows r = 16b + m, DIF stages h=4,2,1
__device__ __forceinline__ void stages_p2(u32 v[16], const uint2* __restrict__ twl){
  #pragma unroll
  for (int g = 0; g < 2; ++g)
    #pragma unroll
    for (int m = 0; m < 4; ++m) bf(v[g*8+m], v[g*8+m+4], twl[m << 4]);      // s=2
  #pragma unroll
  for (int g = 0; g < 4; ++g)
    #pragma unroll
    for (int m = 0; m < 2; ++m) bf(v[g*4+m], v[g*4+m+2], twl[m << 5]);      // s=1
  #pragma unroll
  for (int k = 0; k < 8; ++k) bf0(v[2*k], v[2*k+1]);                        // s=0 (e=0)
}

// LDS swizzle for pass C tile [row=jc(128)][col=ka(128)]: 2-way max aliasing
__device__ __forceinline__ int cidx(int row, int a){
  return (row << 7) | (a ^ (row >> 2));
}
// LDS swizzle for the small [128 row][32 col] tile (pass A small-WG variant)
__device__ __forceinline__ int l16(int row, int col){
  return (row << 5) | (col ^ ((row & 7) << 2));
}

// ------------- table generation: ONE powmod per thread, 257 WGs -------------
extern "C" __global__ void k_gen(uint2* __restrict__ tw, const int* __restrict__ f_intt){
  const u32 tid = blockIdx.x * 256 + threadIdx.x;
  const int intt = f_intt[0];
  const u32 MASK = (1u << 21) - 1;
  u32 v; int dst;
  if (tid < 16384){                       // T_A: w^{hi*lo}
    u32 e = (tid >> 7) * (tid & 127);
    if (intt) e = ((1u<<21) - e) & MASK;
    v = powmod(31u, 960u * e); dst = T_A + tid;
  } else if (tid < 32768){                // T_B: w^{128*hi*lo mod 2^21}
    u32 i = tid - 16384;
    u32 e = (((i >> 7) * (i & 127)) << 7) & MASK;
    if (intt) e = ((1u<<21) - e) & MASK;
    v = powmod(31u, 960u * e); dst = T_B + i;
  } else if (tid < 49152){                // T_W128P: w^{128 i mod 2^21}
    u32 i = tid - 32768;
    u32 e = (i << 7) & MASK;
    if (intt) e = ((1u<<21) - e) & MASK;
    v = powmod(31u, 960u * e); dst = T_W128P + i;
  } else if (tid < 65536){                // T_CLP: c^i (c=7 or 7^-1)
    u32 i = tid - 49152;
    v = intt ? powmod(7u, (MOD_P - 1 - i) % (MOD_P - 1)) : powmod(7u, i);
    dst = T_CLP + i;
  } else if (tid < 65664){                // T_CHP: c^{i<<14}
    u32 e = (tid - 65536) << 14;
    v = intt ? powmod(7u, MOD_P - 1 - e) : powmod(7u, e);
    dst = T_CHP + (tid - 65536);
  } else if (tid < 65728){                // T_RP: w^{i<<14}
    u32 e = ((tid - 65664) << 14) & MASK;
    if (intt) e = ((1u<<21) - e) & MASK;
    v = powmod(31u, 960u * e); dst = T_RP + (tid - 65664);
  } else if (tid == 65728){               // NINV
    v = powmod(1u << 21, MOD_P - 2); dst = T_NINV;
  } else return;
  tw[dst] = make_uint2(v, shoup_of(v));
}

// ==== pass A small-WG: 256 thr, tile [128 ja][32 jc], 8 WG/CU; x -> z =======
// grid: batch*128*4; WG=(batch, jb, jcB). z[batch][jb][ka][jc] contiguous.
extern "C" __global__ void __launch_bounds__(256, 8) k_passA_s(
    const u32* __restrict__ x, u32* __restrict__ z, const uint2* __restrict__ tw,
    const int* __restrict__ f_intt, const int* __restrict__ f_coset)
{
  __shared__ u32 lds[4096];               // [128][32] swizzled
  const int wg = blockIdx.x;
  const int jcB = wg & 3;                 // 32-col block
  const int jb = (wg >> 2) & 127;
  const int batch = wg >> 9;
  const int t = threadIdx.x;
  const u32* xb = x + ((size_t)batch << 21) + (jb << 7) + (jcB << 5);
  u32* zb = z + ((size_t)batch << 21) + (jb << 14) + (jcB << 5);
  const uint2* twl = tw + T_RP;
  {   // stage-in: 128B per row-visit, issue all loads then LDS writes
    const int q = t & 7, rr = t >> 3;     // q: col-quad(4), rr: 0..31
    uint4 tmp[4];
    #pragma unroll
    for (int i = 0; i < 4; ++i)
      tmp[i] = *(const uint4*)(xb + ((size_t)(rr + 32*i) << 14) + (q << 2));
    #pragma unroll
    for (int i = 0; i < 4; ++i){
      u32* d = &lds[l16(rr + 32*i, q << 2)];
      d[0]=redP(tmp[i].x); d[1]=redP(tmp[i].y); d[2]=redP(tmp[i].z); d[3]=redP(tmp[i].w);
    }
  }
  __syncthreads();
  const int c = t & 31;
  const int b = t >> 5;                   // 0..7 (two values per wave)
  const int jc = (jcB << 5) | c;
  u32 v[16];
  #pragma unroll
  for (int m = 0; m < 16; ++m) v[m] = lds[l16(b + 8*m, c)];
  if ((f_intt[0] == 0) && (f_coset[0] != 0)){
    uint2 cl = tw[T_CLP + (jb << 7) + jc];
    #pragma unroll
    for (int m = 0; m < 16; ++m){
      v[m] = mul_shoup(v[m], cl);
      v[m] = mul_shoup(v[m], tw[T_CHP + b + 8*m]);
    }
  }
  stages_p1(v, b, twl);
  #pragma unroll
  for (int m = 0; m < 16; ++m) lds[l16(b + 8*m, c)] = v[m];
  __syncthreads();
  #pragma unroll
  for (int m = 0; m < 16; ++m) v[m] = lds[l16(16*b + m, c)];
  stages_p2(v, twl);
  const int rb = ((b&1)<<2) | (b&2) | ((b&4)>>2);          // rev3(b)
  #pragma unroll
  for (int m = 0; m < 16; ++m){
    const int ka = (rev4(m) << 3) | rb;                    // br7(16b+m)
    u32 vv = mul_shoup(v[m], tw[T_A + (ka << 7) + jc]);    // absorbs [0,2P)
    vv = mul_shoup(vv, tw[T_W128P + ka * jb]);
    zb[(ka << 7) + c] = vv;                                // contiguous-ish
  }
}

// ---- pass B (z-path): strided READ from z, contiguous write to y -----------
extern "C" __global__ void __launch_bounds__(1024, 8) k_passB_z(
    const u32* __restrict__ z, u32* __restrict__ y, const uint2* __restrict__ tw)
{
  __shared__ u32 lds[16384];              // [128 jb][128 jc]
  const int wg = blockIdx.x;
  const int ka = wg & 127;
  const int batch = wg >> 7;
  const int t = threadIdx.x;
  const u32* zb = z + ((size_t)batch << 21) + (ka << 7);
  u32* yb = y + ((size_t)batch << 21) + ((size_t)ka << 14);
  const uint2* twl = tw + T_RP;
  {   // stage-in: z[jb<<14 + ka<<7 + jc] -> 512B segments stride 64KB
    const int q = t & 31, rr = t >> 5;
    uint4 tmp[4];
    #pragma unroll
    for (int i = 0; i < 4; ++i)
      tmp[i] = *(const uint4*)(zb + ((size_t)(rr + 32*i) << 14) + (q << 2));
    #pragma unroll
    for (int i = 0; i < 4; ++i){
      u32* d = &lds[((rr + 32*i) << 7) | (q << 2)];
      d[0]=tmp[i].x; d[1]=tmp[i].y; d[2]=tmp[i].z; d[3]=tmp[i].w;
    }
  }
  __syncthreads();
  const int jc = t & 127;
  const int b = __builtin_amdgcn_readfirstlane(t >> 7);
  u32 v[16];
  #pragma unroll
  for (int m = 0; m < 16; ++m) v[m] = lds[((b + 8*m) << 7) | jc];
  stages_p1(v, b, twl);
  #pragma unroll
  for (int m = 0; m < 16; ++m) lds[((b + 8*m) << 7) | jc] = v[m];
  __syncthreads();
  #pragma unroll
  for (int m = 0; m < 16; ++m) v[m] = lds[((16*b + m) << 7) | jc];
  stages_p2(v, twl);
  const int rb = ((b&1)<<2) | (b&2) | ((b&4)>>2);
  #pragma unroll
  for (int m = 0; m < 16; ++m){
    const int kb = (rev4(m) << 3) | rb;
    u32 vv = mul_shoup(v[m], tw[T_B + (kb << 7) + jc]);    // absorbs [0,2P)
    yb[(kb << 7) + jc] = vv;                               // contiguous slab
  }
}

// ------- pass C: NTT over jc + in-place plane transpose to final order ------
extern "C" __global__ void __launch_bounds__(1024, 8) k_passC(
    u32* __restrict__ y, const uint2* __restrict__ tw,
    const int* __restrict__ f_intt, const int* __restrict__ f_coset)
{
  __shared__ u32 lds[16384];
  const int wg = blockIdx.x;
  const int kb = wg & 127;
  const int batch = wg >> 7;
  u32* yb = y + ((size_t)batch << 21);
  const u32* base = yb + (kb << 7);
  const int t = threadIdx.x;
  {   // stage-in: issue all loads, then swizzled LDS transpose writes
    const int q = t & 31;
    const int rr = t >> 5;
    uint4 tmp[4];
    #pragma unroll
    for (int i = 0; i < 4; ++i)
      tmp[i] = *(const uint4*)(base + ((size_t)(rr + 32*i) << 14) + (q << 2));
    #pragma unroll
    for (int i = 0; i < 4; ++i){
      int kaL = rr + 32*i;
      lds[cidx(4*q+0, kaL)] = tmp[i].x;
      lds[cidx(4*q+1, kaL)] = tmp[i].y;
      lds[cidx(4*q+2, kaL)] = tmp[i].z;
      lds[cidx(4*q+3, kaL)] = tmp[i].w;
    }
  }
  __syncthreads();
  const int a = t & 127;
  const int b = __builtin_amdgcn_readfirstlane(t >> 7);
  const uint2* twl = tw + T_RP;
  u32 v[16];
  #pragma unroll
  for (int m = 0; m < 16; ++m) v[m] = lds[cidx(b + 8*m, a)];
  stages_p1(v, b, twl);
  #pragma unroll
  for (int m = 0; m < 16; ++m) lds[cidx(b + 8*m, a)] = v[m];
  __syncthreads();
  #pragma unroll
  for (int m = 0; m < 16; ++m) v[m] = lds[cidx(16*b + m, a)];
  stages_p2(v, twl);
  const int rb = ((b&1)<<2) | (b&2) | ((b&4)>>2);
  const int intt = f_intt[0];
  const int coset = f_coset[0];
  #pragma unroll
  for (int m = 0; m < 16; ++m){
    const int kc = (rev4(m) << 3) | rb;
    u32 vv = v[m];
    if (intt){
      vv = mul_shoup(vv, tw[T_NINV]);
      if (coset){
        vv = mul_shoup(vv, tw[T_CLP + (kb << 7) + a]);
        vv = mul_shoup(vv, tw[T_CHP + kc]);
      }
    } else {
      vv = redP(vv);
    }
    // final output is dead data for the next replay: keep it out of L3
    __builtin_nontemporal_store(vv, yb + ((size_t)kc << 14) + (kb << 7) + a);
  }
}

// ---------------- fallback pass A (round-8 proven): x -> y strided ----------
extern "C" __global__ void __launch_bounds__(1024, 8) k_passA(
    const u32* __restrict__ x, u32* __restrict__ y, const uint2* __restrict__ tw,
    const int* __restrict__ f_intt, const int* __restrict__ f_coset)
{
  __shared__ u32 lds[16384];
  const int wg = blockIdx.x;
  const int jb = wg & 127;
  const int batch = wg >> 7;
  const int t = threadIdx.x;
  const u32* xb = x + ((size_t)batch << 21) + (jb << 7);
  u32* yb = y + ((size_t)batch << 21);
  const uint2* twl = tw + T_RP;
  {
    const int q = t & 31, rr = t >> 5;
    uint4 tmp[4];
    #pragma unroll
    for (int i = 0; i < 4; ++i)
      tmp[i] = *(const uint4*)(xb + ((size_t)(rr + 32*i) << 14) + (q << 2));
    #pragma unroll
    for (int i = 0; i < 4; ++i){
      u32* d = &lds[((rr + 32*i) << 7) | (q << 2)];
      d[0] = redP(tmp[i].x); d[1] = redP(tmp[i].y);
      d[2] = redP(tmp[i].z); d[3] = redP(tmp[i].w);
    }
  }
  __syncthreads();
  const int jc = t & 127;
  const int b = __builtin_amdgcn_readfirstlane(t >> 7);
  u32 v[16];
  #pragma unroll
  for (int m = 0; m < 16; ++m) v[m] = lds[((b + 8*m) << 7) | jc];
  if ((f_intt[0] == 0) && (f_coset[0] != 0)){
    uint2 cl = tw[T_CLP + (jb << 7) + jc];
    #pragma unroll
    for (int m = 0; m < 16; ++m){
      v[m] = mul_shoup(v[m], cl);
      v[m] = mul_shoup(v[m], tw[T_CHP + b + 8*m]);
    }
  }
  stages_p1(v, b, twl);
  #pragma unroll
  for (int m = 0; m < 16; ++m) lds[((b + 8*m) << 7) | jc] = v[m];
  __syncthreads();
  #pragma unroll
  for (int m = 0; m < 16; ++m) v[m] = lds[((16*b + m) << 7) | jc];
  stages_p2(v, twl);
  const int rb = ((b&1)<<2) | (b&2) | ((b&4)>>2);
  #pragma unroll
  for (int m = 0; m < 16; ++m){
    const int ka = (rev4(m) << 3) | rb;
    u32 vv = mul_shoup(v[m], tw[T_A + (ka << 7) + jc]);
    vv = mul_shoup(vv, tw[T_W128P + ka * jb]);
    yb[((size_t)ka << 14) + (jb << 7) + jc] = vv;
  }
}

// ---------------- fallback pass B (round-8 proven): y in-place --------------
extern "C" __global__ void __launch_bounds__(1024, 8) k_passB(
    u32* __restrict__ y, const uint2* __restrict__ tw)
{
  __shared__ u32 lds[16384];
  const int wg = blockIdx.x;
  const int ka = wg & 127;
  const int batch = wg >> 7;
  const int t = threadIdx.x;
  u32* yb = y + ((size_t)batch << 21) + ((size_t)ka << 14);
  const uint2* twl = tw + T_RP;
  {
    const uint4* s4 = (const uint4*)yb;
    uint4* l4 = (uint4*)lds;
    #pragma unroll
    for (int i = 0; i < 4; ++i) l4[t + 1024*i] = s4[t + 1024*i];
  }
  __syncthreads();
  const int jc = t & 127;
  const int b = __builtin_amdgcn_readfirstlane(t >> 7);
  u32 v[16];
  #pragma unroll
  for (int m = 0; m < 16; ++m) v[m] = lds[((b + 8*m) << 7) | jc];
  stages_p1(v, b, twl);
  #pragma unroll
  for (int m = 0; m < 16; ++m) lds[((b + 8*m) << 7) | jc] = v[m];
  __syncthreads();
  #pragma unroll
  for (int m = 0; m < 16; ++m) v[m] = lds[((16*b + m) << 7) | jc];
  stages_p2(v, twl);
  const int rb = ((b&1)<<2) | (b&2) | ((b&4)>>2);
  #pragma unroll
  for (int m = 0; m < 16; ++m){
    const int kb = (rev4(m) << 3) | rb;
    u32 vv = mul_shoup(v[m], tw[T_B + (kb << 7) + jc]);
    yb[(kb << 7) + jc] = vv;
  }
}

extern "C" void kernel_launch(void* const* d_in, const int* in_sizes, int n_in,
                              void* d_out, int out_size, void* d_ws, size_t ws_size,
                              hipStream_t stream)
{
  const u32* x = (const u32*)d_in[0];
  const int* f_intt  = (const int*)d_in[1];
  const int* f_coset = (const int*)d_in[2];
  u32* y   = (u32*)d_out;
  uint2* tw = (uint2*)d_ws;
  const int batch = in_sizes[0] >> 21;     // 8
  const int nwg = batch << 7;              // 1024 tile-units per pass

  k_gen<<<257, 256, 0, stream>>>(tw, f_intt);

  const size_t zoff = (size_t)1 << 20;                 // tables live in [0,1MB)
  const size_t need = zoff + ((size_t)batch << 23);    // + 64MB scratch
  if (ws_size >= need){
    u32* z = (u32*)((char*)d_ws + zoff);
    k_passA_s<<<batch << 9, 256, 0, stream>>>(x, z, tw, f_intt, f_coset);
    k_passB_z<<<nwg, 1024, 0, stream>>>(z, y, tw);
  } else {
    k_passA<<<nwg, 1024, 0, stream>>>(x, y, tw, f_intt, f_coset);
    k_passB<<<nwg, 1024, 0, stream>>>(y, tw);
  }
  k_passC<<<nwg, 1024, 0, stream>>>(y, tw, f_intt, f_coset);
}

// Round 13
// 100.018 us; speedup vs baseline: 1.3838x; 1.0312x over previous
//
#include <hip/hip_runtime.h>
#include <stdint.h>

typedef unsigned int u32;
typedef unsigned long long u64;

#define MOD_P 2013265921u

// uint2 table offsets (index in uint2 units): (value, shoup) pairs
#define T_A      0        // w^{(i>>7)*(i&127)}        [ka][jc] product table, 16384
#define T_B      16384    // (w^128)^{(i>>7)*(i&127)}  [kb][jc] product table, 16384
#define T_W128P  32768    // (w^128)^i, i<16384
#define T_RP     49152    // (w^16384)^i, i<64  (order-128 stage roots)
#define T_CLP    49216    // c^i, i<16384       (coset low)
#define T_CHP    65600    // c^(16384 i), i<128 (coset high)
#define T_NINV   65728    // (n^-1)

__device__ __forceinline__ u32 mul64mod(u32 a, u32 b){ return (u32)((u64)a * b % MOD_P); }

__device__ u32 powmod(u32 b, u32 e){
  u32 r = 1;
  while (e){ if (e & 1) r = mul64mod(r, b); b = mul64mod(b, b); e >>= 1; }
  return r;
}

__device__ __forceinline__ u32 shoup_of(u32 v){ return (u32)(((u64)v << 32) / MOD_P); }

// reduce a in [0,2P) to [0,P): v_sub + v_min_u32 (unsigned-wrap min trick)
__device__ __forceinline__ u32 redP(u32 a){
  u32 b = a - MOD_P;
  return b < a ? b : a;
}

// Shoup modular multiply; valid for ANY a < 2^32 (w < P): r = a*w mod P in [0,P)
__device__ __forceinline__ u32 mul_shoup(u32 a, uint2 t){
  u32 q = __umulhi(a, t.y);
  u32 r = a * t.x - q * MOD_P;          // exact mod 2^32, true value < 2P
  return redP(r);
}

__device__ __forceinline__ constexpr int rev4(int m){
  return ((m&1)<<3) | ((m&2)<<1) | ((m&4)>>1) | ((m&8)>>3);
}

// DIF butterfly: (x,y) -> (x+y mod P, (x-y)*t mod P); inputs in [0,P)
__device__ __forceinline__ void bf(u32 &x, u32 &y, uint2 t){
  u32 s = redP(x + y);
  u32 d = x - y + MOD_P;                // in (0,2P) — mul_shoup absorbs
  x = s; y = mul_shoup(d, t);
}
// last stage, twiddle=1: y left in [0,2P) (consumer must absorb or redP)
__device__ __forceinline__ void bf0(u32 &x, u32 &y){
  u32 s = redP(x + y);
  u32 d = x - y + MOD_P;
  x = s; y = d;
}

// phase-1: thread rows r = b + 8m (m=0..15), DIF stages h=64,32,16,8
__device__ __forceinline__ void stages_p1(u32 v[16], int b, const uint2* __restrict__ twl){
  #pragma unroll
  for (int m = 0; m < 8; ++m) bf(v[m], v[m+8], twl[b + 8*m]);               // s=6
  #pragma unroll
  for (int g = 0; g < 2; ++g)
    #pragma unroll
    for (int m = 0; m < 4; ++m) bf(v[g*8+m], v[g*8+m+4], twl[(b + 8*m) << 1]); // s=5
  #pragma unroll
  for (int g = 0; g < 4; ++g)
    #pragma unroll
    for (int m = 0; m < 2; ++m) bf(v[g*4+m], v[g*4+m+2], twl[(b + 8*m) << 2]); // s=4
  #pragma unroll
  for (int k = 0; k < 8; ++k) bf(v[2*k], v[2*k+1], twl[b << 3]);            // s=3
}
// phase-2: thread rows r = 16b + m, DIF stages h=4,2,1
__device__ __forceinline__ void stages_p2(u32 v[16], const uint2* __restrict__ twl){
  #pragma unroll
  for (int g = 0; g < 2; ++g)
    #pragma unroll
    for (int m = 0; m < 4; ++m) bf(v[g*8+m], v[g*8+m+4], twl[m << 4]);      // s=2
  #pragma unroll
  for (int g = 0; g < 4; ++g)
    #pragma unroll
    for (int m = 0; m < 2; ++m) bf(v[g*4+m], v[g*4+m+2], twl[m << 5]);      // s=1
  #pragma unroll
  for (int k = 0; k < 8; ++k) bf0(v[2*k], v[2*k+1]);                        // s=0 (e=0)
}

// LDS swizzle for pass C tile [row=jc(128)][col=ka(128)]: 2-way max aliasing
__device__ __forceinline__ int cidx(int row, int a){
  return (row << 7) | (a ^ (row >> 2));
}

// ------------- table generation: ONE powmod per thread, 257 WGs -------------
extern "C" __global__ void k_gen(uint2* __restrict__ tw, const int* __restrict__ f_intt){
  const u32 tid = blockIdx.x * 256 + threadIdx.x;
  const int intt = f_intt[0];
  const u32 MASK = (1u << 21) - 1;
  u32 v; int dst;
  if (tid < 16384){                       // T_A: w^{hi*lo}
    u32 e = (tid >> 7) * (tid & 127);
    if (intt) e = ((1u<<21) - e) & MASK;
    v = powmod(31u, 960u * e); dst = T_A + tid;
  } else if (tid < 32768){                // T_B: w^{128*hi*lo mod 2^21}
    u32 i = tid - 16384;
    u32 e = (((i >> 7) * (i & 127)) << 7) & MASK;
    if (intt) e = ((1u<<21) - e) & MASK;
    v = powmod(31u, 960u * e); dst = T_B + i;
  } else if (tid < 49152){                // T_W128P: w^{128 i mod 2^21}
    u32 i = tid - 32768;
    u32 e = (i << 7) & MASK;
    if (intt) e = ((1u<<21) - e) & MASK;
    v = powmod(31u, 960u * e); dst = T_W128P + i;
  } else if (tid < 65536){                // T_CLP: c^i (c=7 or 7^-1)
    u32 i = tid - 49152;
    v = intt ? powmod(7u, (MOD_P - 1 - i) % (MOD_P - 1)) : powmod(7u, i);
    dst = T_CLP + i;
  } else if (tid < 65664){                // T_CHP: c^{i<<14}
    u32 e = (tid - 65536) << 14;
    v = intt ? powmod(7u, MOD_P - 1 - e) : powmod(7u, e);
    dst = T_CHP + (tid - 65536);
  } else if (tid < 65728){                // T_RP: w^{i<<14}
    u32 e = ((tid - 65664) << 14) & MASK;
    if (intt) e = ((1u<<21) - e) & MASK;
    v = powmod(31u, 960u * e); dst = T_RP + (tid - 65664);
  } else if (tid == 65728){               // NINV
    v = powmod(1u << 21, MOD_P - 2); dst = T_NINV;
  } else return;
  tw[dst] = make_uint2(v, shoup_of(v));
}

// ---- pass A (z-path): NTT over ja; strided READ, CONTIGUOUS write to z -----
// z layout: z[batch][jb][ka][jc] -> contiguous 64KB per WG
extern "C" __global__ void __launch_bounds__(1024, 8) k_passA_z(
    const u32* __restrict__ x, u32* __restrict__ z, const uint2* __restrict__ tw,
    const int* __restrict__ f_intt, const int* __restrict__ f_coset)
{
  __shared__ u32 lds[16384];              // [128 ja][128 jc] natural
  const int wg = blockIdx.x;
  const int jb = wg & 127;
  const int batch = wg >> 7;
  const int t = threadIdx.x;
  const u32* xb = x + ((size_t)batch << 21) + (jb << 7);
  u32* zb = z + ((size_t)batch << 21) + (jb << 14);
  const uint2* twl = tw + T_RP;
  {   // stage-in: issue ALL loads first, then LDS writes (max loads in flight)
    const int q = t & 31, rr = t >> 5;    // q: jc-quad, rr: 0..31
    uint4 tmp[4];
    #pragma unroll
    for (int i = 0; i < 4; ++i)
      tmp[i] = *(const uint4*)(xb + ((size_t)(rr + 32*i) << 14) + (q << 2));
    #pragma unroll
    for (int i = 0; i < 4; ++i){
      u32* d = &lds[((rr + 32*i) << 7) | (q << 2)];
      d[0]=redP(tmp[i].x); d[1]=redP(tmp[i].y); d[2]=redP(tmp[i].z); d[3]=redP(tmp[i].w);
    }
  }
  __syncthreads();
  const int jc = t & 127;
  const int b = __builtin_amdgcn_readfirstlane(t >> 7);   // 0..7, wave-uniform
  u32 v[16];
  #pragma unroll
  for (int m = 0; m < 16; ++m) v[m] = lds[((b + 8*m) << 7) | jc];
  if ((f_intt[0] == 0) && (f_coset[0] != 0)){
    uint2 cl = tw[T_CLP + (jb << 7) + jc];
    #pragma unroll
    for (int m = 0; m < 16; ++m){
      v[m] = mul_shoup(v[m], cl);
      v[m] = mul_shoup(v[m], tw[T_CHP + b + 8*m]);
    }
  }
  stages_p1(v, b, twl);
  #pragma unroll
  for (int m = 0; m < 16; ++m) lds[((b + 8*m) << 7) | jc] = v[m];
  __syncthreads();
  #pragma unroll
  for (int m = 0; m < 16; ++m) v[m] = lds[((16*b + m) << 7) | jc];
  stages_p2(v, twl);
  const int rb = ((b&1)<<2) | (b&2) | ((b&4)>>2);          // rev3(b)
  #pragma unroll
  for (int m = 0; m < 16; ++m){
    const int ka = (rev4(m) << 3) | rb;                    // br7(16b+m)
    u32 vv = mul_shoup(v[m], tw[T_A + (ka << 7) + jc]);    // absorbs [0,2P)
    vv = mul_shoup(vv, tw[T_W128P + ka * jb]);             // wave-uniform
    zb[(ka << 7) + jc] = vv;                               // contiguous block
  }
}

// ---- pass B (z-path): strided READ from z, contiguous write to y -----------
extern "C" __global__ void __launch_bounds__(1024, 8) k_passB_z(
    const u32* __restrict__ z, u32* __restrict__ y, const uint2* __restrict__ tw)
{
  __shared__ u32 lds[16384];              // [128 jb][128 jc]
  const int wg = blockIdx.x;
  const int ka = wg & 127;
  const int batch = wg >> 7;
  const int t = threadIdx.x;
  const u32* zb = z + ((size_t)batch << 21) + (ka << 7);
  u32* yb = y + ((size_t)batch << 21) + ((size_t)ka << 14);
  const uint2* twl = tw + T_RP;
  {   // stage-in: z[jb<<14 + ka<<7 + jc] -> 512B segments stride 64KB
    const int q = t & 31, rr = t >> 5;
    uint4 tmp[4];
    #pragma unroll
    for (int i = 0; i < 4; ++i)
      tmp[i] = *(const uint4*)(zb + ((size_t)(rr + 32*i) << 14) + (q << 2));
    #pragma unroll
    for (int i = 0; i < 4; ++i){
      u32* d = &lds[((rr + 32*i) << 7) | (q << 2)];
      d[0]=tmp[i].x; d[1]=tmp[i].y; d[2]=tmp[i].z; d[3]=tmp[i].w;
    }
  }
  __syncthreads();
  const int jc = t & 127;
  const int b = __builtin_amdgcn_readfirstlane(t >> 7);
  u32 v[16];
  #pragma unroll
  for (int m = 0; m < 16; ++m) v[m] = lds[((b + 8*m) << 7) | jc];
  stages_p1(v, b, twl);
  #pragma unroll
  for (int m = 0; m < 16; ++m) lds[((b + 8*m) << 7) | jc] = v[m];
  __syncthreads();
  #pragma unroll
  for (int m = 0; m < 16; ++m) v[m] = lds[((16*b + m) << 7) | jc];
  stages_p2(v, twl);
  const int rb = ((b&1)<<2) | (b&2) | ((b&4)>>2);
  #pragma unroll
  for (int m = 0; m < 16; ++m){
    const int kb = (rev4(m) << 3) | rb;
    u32 vv = mul_shoup(v[m], tw[T_B + (kb << 7) + jc]);    // absorbs [0,2P)
    yb[(kb << 7) + jc] = vv;                               // contiguous slab
  }
}

// ---------------- fallback pass A (round-8 proven): x -> y strided ----------
extern "C" __global__ void __launch_bounds__(1024, 8) k_passA(
    const u32* __restrict__ x, u32* __restrict__ y, const uint2* __restrict__ tw,
    const int* __restrict__ f_intt, const int* __restrict__ f_coset)
{
  __shared__ u32 lds[16384];
  const int wg = blockIdx.x;
  const int jb = wg & 127;
  const int batch = wg >> 7;
  const int t = threadIdx.x;
  const u32* xb = x + ((size_t)batch << 21) + (jb << 7);
  u32* yb = y + ((size_t)batch << 21);
  const uint2* twl = tw + T_RP;
  {
    const int q = t & 31, rr = t >> 5;
    uint4 tmp[4];
    #pragma unroll
    for (int i = 0; i < 4; ++i)
      tmp[i] = *(const uint4*)(xb + ((size_t)(rr + 32*i) << 14) + (q << 2));
    #pragma unroll
    for (int i = 0; i < 4; ++i){
      u32* d = &lds[((rr + 32*i) << 7) | (q << 2)];
      d[0] = redP(tmp[i].x); d[1] = redP(tmp[i].y);
      d[2] = redP(tmp[i].z); d[3] = redP(tmp[i].w);
    }
  }
  __syncthreads();
  const int jc = t & 127;
  const int b = __builtin_amdgcn_readfirstlane(t >> 7);
  u32 v[16];
  #pragma unroll
  for (int m = 0; m < 16; ++m) v[m] = lds[((b + 8*m) << 7) | jc];
  if ((f_intt[0] == 0) && (f_coset[0] != 0)){
    uint2 cl = tw[T_CLP + (jb << 7) + jc];
    #pragma unroll
    for (int m = 0; m < 16; ++m){
      v[m] = mul_shoup(v[m], cl);
      v[m] = mul_shoup(v[m], tw[T_CHP + b + 8*m]);
    }
  }
  stages_p1(v, b, twl);
  #pragma unroll
  for (int m = 0; m < 16; ++m) lds[((b + 8*m) << 7) | jc] = v[m];
  __syncthreads();
  #pragma unroll
  for (int m = 0; m < 16; ++m) v[m] = lds[((16*b + m) << 7) | jc];
  stages_p2(v, twl);
  const int rb = ((b&1)<<2) | (b&2) | ((b&4)>>2);
  #pragma unroll
  for (int m = 0; m < 16; ++m){
    const int ka = (rev4(m) << 3) | rb;
    u32 vv = mul_shoup(v[m], tw[T_A + (ka << 7) + jc]);
    vv = mul_shoup(vv, tw[T_W128P + ka * jb]);
    yb[((size_t)ka << 14) + (jb << 7) + jc] = vv;
  }
}

// ---------------- fallback pass B (round-8 proven): y in-place --------------
extern "C" __global__ void __launch_bounds__(1024, 8) k_passB(
    u32* __restrict__ y, const uint2* __restrict__ tw)
{
  __shared__ u32 lds[16384];
  const int wg = blockIdx.x;
  const int ka = wg & 127;
  const int batch = wg >> 7;
  const int t = threadIdx.x;
  u32* yb = y + ((size_t)batch << 21) + ((size_t)ka << 14);
  const uint2* twl = tw + T_RP;
  {
    const uint4* s4 = (const uint4*)yb;
    uint4* l4 = (uint4*)lds;
    #pragma unroll
    for (int i = 0; i < 4; ++i) l4[t + 1024*i] = s4[t + 1024*i];
  }
  __syncthreads();
  const int jc = t & 127;
  const int b = __builtin_amdgcn_readfirstlane(t >> 7);
  u32 v[16];
  #pragma unroll
  for (int m = 0; m < 16; ++m) v[m] = lds[((b + 8*m) << 7) | jc];
  stages_p1(v, b, twl);
  #pragma unroll
  for (int m = 0; m < 16; ++m) lds[((b + 8*m) << 7) | jc] = v[m];
  __syncthreads();
  #pragma unroll
  for (int m = 0; m < 16; ++m) v[m] = lds[((16*b + m) << 7) | jc];
  stages_p2(v, twl);
  const int rb = ((b&1)<<2) | (b&2) | ((b&4)>>2);
  #pragma unroll
  for (int m = 0; m < 16; ++m){
    const int kb = (rev4(m) << 3) | rb;
    u32 vv = mul_shoup(v[m], tw[T_B + (kb << 7) + jc]);
    yb[(kb << 7) + jc] = vv;
  }
}

// ------- pass C: NTT over jc + in-place plane transpose to final order ------
extern "C" __global__ void __launch_bounds__(1024, 8) k_passC(
    u32* __restrict__ y, const uint2* __restrict__ tw,
    const int* __restrict__ f_intt, const int* __restrict__ f_coset)
{
  __shared__ u32 lds[16384];
  const int wg = blockIdx.x;
  const int kb = wg & 127;
  const int batch = wg >> 7;
  u32* yb = y + ((size_t)batch << 21);
  const u32* base = yb + (kb << 7);
  const int t = threadIdx.x;
  {   // stage-in: issue all loads, then swizzled LDS transpose writes
    const int q = t & 31;
    const int rr = t >> 5;
    uint4 tmp[4];
    #pragma unroll
    for (int i = 0; i < 4; ++i)
      tmp[i] = *(const uint4*)(base + ((size_t)(rr + 32*i) << 14) + (q << 2));
    #pragma unroll
    for (int i = 0; i < 4; ++i){
      int kaL = rr + 32*i;
      lds[cidx(4*q+0, kaL)] = tmp[i].x;
      lds[cidx(4*q+1, kaL)] = tmp[i].y;
      lds[cidx(4*q+2, kaL)] = tmp[i].z;
      lds[cidx(4*q+3, kaL)] = tmp[i].w;
    }
  }
  __syncthreads();
  const int a = t & 127;
  const int b = __builtin_amdgcn_readfirstlane(t >> 7);
  const uint2* twl = tw + T_RP;
  u32 v[16];
  #pragma unroll
  for (int m = 0; m < 16; ++m) v[m] = lds[cidx(b + 8*m, a)];
  stages_p1(v, b, twl);
  #pragma unroll
  for (int m = 0; m < 16; ++m) lds[cidx(b + 8*m, a)] = v[m];
  __syncthreads();
  #pragma unroll
  for (int m = 0; m < 16; ++m) v[m] = lds[cidx(16*b + m, a)];
  stages_p2(v, twl);
  const int rb = ((b&1)<<2) | (b&2) | ((b&4)>>2);
  const int intt = f_intt[0];
  const int coset = f_coset[0];
  #pragma unroll
  for (int m = 0; m < 16; ++m){
    const int kc = (rev4(m) << 3) | rb;
    u32 vv = v[m];
    if (intt){
      vv = mul_shoup(vv, tw[T_NINV]);
      if (coset){
        vv = mul_shoup(vv, tw[T_CLP + (kb << 7) + a]);
        vv = mul_shoup(vv, tw[T_CHP + kc]);
      }
    } else {
      vv = redP(vv);
    }
    __builtin_nontemporal_store(vv, yb + ((size_t)kc << 14) + (kb << 7) + a);
  }
}

extern "C" void kernel_launch(void* const* d_in, const int* in_sizes, int n_in,
                              void* d_out, int out_size, void* d_ws, size_t ws_size,
                              hipStream_t stream)
{
  const u32* x = (const u32*)d_in[0];
  const int* f_intt  = (const int*)d_in[1];
  const int* f_coset = (const int*)d_in[2];
  u32* y   = (u32*)d_out;
  uint2* tw = (uint2*)d_ws;
  const int batch = in_sizes[0] >> 21;     // 8
  const int nwg = batch << 7;              // 1024 workgroups per pass

  k_gen<<<257, 256, 0, stream>>>(tw, f_intt);

  const size_t zoff = (size_t)1 << 20;                 // tables live in [0,1MB)
  const size_t need = zoff + ((size_t)batch << 23);    // + 64MB scratch
  if (ws_size >= need){
    u32* z = (u32*)((char*)d_ws + zoff);
    k_passA_z<<<nwg, 1024, 0, stream>>>(x, z, tw, f_intt, f_coset);
    k_passB_z<<<nwg, 1024, 0, stream>>>(z, y, tw);
  } else {
    k_passA<<<nwg, 1024, 0, stream>>>(x, y, tw, f_intt, f_coset);
    k_passB<<<nwg, 1024, 0, stream>>>(y, tw);
  }
  k_passC<<<nwg, 1024, 0, stream>>>(y, tw, f_intt, f_coset);
}